// Round 5
// baseline (232.996 us; speedup 1.0000x reference)
//
#include <hip/hip_runtime.h>
#include <hip/hip_bf16.h>
#include <stdint.h>

typedef unsigned short u16;
typedef unsigned int u32;
typedef __attribute__((ext_vector_type(8))) short short8;    // 8 bf16 = 4 VGPR (MFMA A/B frag)
typedef __attribute__((ext_vector_type(4))) short short4e;   // 8B packed store
typedef __attribute__((ext_vector_type(4))) float f32x4;     // 16x16 MFMA C/D frag
typedef __attribute__((ext_vector_type(16))) float f32x16;   // 32x32 MFMA C/D frag

constexpr int CB = 2, CS = 2048, CD = 1024, CH = 16, CHD = 64;
constexpr float SC2 = 0.125f * 1.44269504088896f;   // scale * log2(e): exp2 domain
constexpr float DEFER_THR = 11.0f;                  // P bounded by 2^11

__device__ __forceinline__ u16 f2bf(float f) {
    unsigned u = __float_as_uint(f);
    u += 0x7fffu + ((u >> 16) & 1u);     // RNE
    return (u16)(u >> 16);
}

#if __has_builtin(__builtin_amdgcn_exp2f)
#define EXP2F(x) __builtin_amdgcn_exp2f(x)
#else
#define EXP2F(x) exp2f(x)
#endif

// pack two f32 -> u32 of 2 bf16 (lo = a, hi = b)
__device__ __forceinline__ u32 pkbf(float a, float b) {
    u32 r;
    asm("v_cvt_pk_bf16_f32 %0, %1, %2" : "=v"(r) : "v"(a), "v"(b));
    return r;
}

// ---------------------------------------------------------------------------
// f32 -> bf16 elementwise (x). 8 elems/thread, exact grid.
// ---------------------------------------------------------------------------
__global__ __launch_bounds__(256) void cvt_x(const float* __restrict__ X, u16* __restrict__ Y) {
    const int i = (blockIdx.x * 256 + threadIdx.x) * 8;
    const float4 v0 = *(const float4*)(X + i);
    const float4 v1 = *(const float4*)(X + i + 4);
    short8 r;
    r[0] = (short)f2bf(v0.x); r[1] = (short)f2bf(v0.y);
    r[2] = (short)f2bf(v0.z); r[3] = (short)f2bf(v0.w);
    r[4] = (short)f2bf(v1.x); r[5] = (short)f2bf(v1.y);
    r[6] = (short)f2bf(v1.z); r[7] = (short)f2bf(v1.w);
    *(short8*)(Y + i) = r;
}

// ---------------------------------------------------------------------------
// Transpose + convert: W [1024][N] f32  ->  Bt [N][1024] bf16.  64x64 tiles.
// ---------------------------------------------------------------------------
__global__ __launch_bounds__(256) void txw(const float* __restrict__ W, u16* __restrict__ Bt,
                                           int ldw) {
    __shared__ u16 T[64][80];
    const int t = threadIdx.x;
    const int n0 = blockIdx.x * 64, k0 = blockIdx.y * 64;
    const int r = t >> 4, c4 = (t & 15) * 4;
#pragma unroll
    for (int p = 0; p < 4; ++p) {
        const int kr = r + p * 16;
        const float4 v = *(const float4*)(W + (size_t)(k0 + kr) * ldw + n0 + c4);
        T[c4 + 0][kr] = f2bf(v.x); T[c4 + 1][kr] = f2bf(v.y);
        T[c4 + 2][kr] = f2bf(v.z); T[c4 + 3][kr] = f2bf(v.w);
    }
    __syncthreads();
    const int rr = t >> 2, cc = (t & 3) * 16;
    const short8 a = *(const short8*)((const char*)&T[0][0] + rr * 160 + cc * 2);
    const short8 b = *(const short8*)((const char*)&T[0][0] + rr * 160 + cc * 2 + 16);
    u16* dst = Bt + (size_t)(n0 + rr) * 1024 + k0 + cc;
    *(short8*)dst = a;
    *(short8*)(dst + 8) = b;
}

// ---------------------------------------------------------------------------
// bf16 MFMA GEMM, 128x128 tile, BK=32, 4 waves (2x2), double-buffered LDS,
// async global_load_lds (width 16) staging, 1 barrier per K-step.  K = 1024.
// LDS layout is linear in lane order (gload_lds writes base + lane*16).
// mode 0: scatter QKV per head; Q pre-scaled by SC2. mode 1: f32 write.
// ---------------------------------------------------------------------------
__global__ __launch_bounds__(256) void gemm_mfma(
    const u16* __restrict__ A, const u16* __restrict__ Bt, int mode,
    u16* __restrict__ Qws, u16* __restrict__ Kws, u16* __restrict__ Vtws,
    float* __restrict__ Cf)
{
    __shared__ u16 SB[2][8192];
    const int tid = threadIdx.x;
    const int w = tid >> 6, lane = tid & 63;
    const int l15 = lane & 15, l4 = lane >> 4;
    const int wr = w >> 1, wc = w & 1;
    const int n0 = blockIdx.x * 128, m0 = blockIdx.y * 128;

    f32x4 acc[4][4];
    const f32x4 zf = {0.f, 0.f, 0.f, 0.f};
#pragma unroll
    for (int i = 0; i < 4; ++i)
#pragma unroll
        for (int j = 0; j < 4; ++j) acc[i][j] = zf;

    // chunk c = tid + it*256 (c<512: A-tile, else B-tile); LDS byte off = c*16.
#define GEMM_STAGE(BUF, K0)                                                     \
    {                                                                           \
        _Pragma("unroll")                                                       \
        for (int it = 0; it < 4; ++it) {                                        \
            const int c = tid + it * 256;                                       \
            const u16* src;                                                     \
            if (c < 512) { const int row = c >> 2, cs = c & 3;                  \
                src = A + (size_t)(m0 + row) * 1024 + (K0) + cs * 8; }          \
            else { const int c2 = c - 512; const int row = c2 >> 2, cs = c2 & 3;\
                src = Bt + (size_t)(n0 + row) * 1024 + (K0) + cs * 8; }         \
            __builtin_amdgcn_global_load_lds(                                   \
                (const __attribute__((address_space(1))) unsigned int*)src,     \
                (__attribute__((address_space(3))) unsigned int*)&SB[BUF][c*8], \
                16, 0, 0);                                                      \
        }                                                                       \
    }

    GEMM_STAGE(0, 0);
    __syncthreads();

    for (int t = 0; t < 32; ++t) {
        const int cur = t & 1;
        if (t < 31) GEMM_STAGE(cur ^ 1, (t + 1) * 32);

        const u16* Al = &SB[cur][0];
        const u16* Bl = &SB[cur][4096];
        short8 a[4], b[4];
#pragma unroll
        for (int i = 0; i < 4; ++i)
            a[i] = *(const short8*)(Al + (wr * 64 + i * 16 + l15) * 32 + l4 * 8);
#pragma unroll
        for (int j = 0; j < 4; ++j)
            b[j] = *(const short8*)(Bl + (wc * 64 + j * 16 + l15) * 32 + l4 * 8);
        __builtin_amdgcn_s_setprio(1);
#pragma unroll
        for (int i = 0; i < 4; ++i)
#pragma unroll
            for (int j = 0; j < 4; ++j)
                acc[i][j] = __builtin_amdgcn_mfma_f32_16x16x32_bf16(a[i], b[j], acc[i][j], 0, 0, 0);
        __builtin_amdgcn_s_setprio(0);
        __syncthreads();
    }

    // C/D layout (16x16): col = lane&15, row = (lane>>4)*4 + reg.
    if (mode == 1) {
#pragma unroll
        for (int i = 0; i < 4; ++i)
#pragma unroll
            for (int j = 0; j < 4; ++j)
#pragma unroll
                for (int r = 0; r < 4; ++r)
                    Cf[(size_t)(m0 + wr * 64 + i * 16 + l4 * 4 + r) * 1024 +
                       n0 + wc * 64 + j * 16 + l15] = acc[i][j][r];
    } else {
        const int e0 = n0 + wc * 64;
        const int which = e0 >> 10;
        const int h = (e0 >> 6) & 15;
        const int b = m0 >> 11;
        const int sbase = (m0 & 2047) + wr * 64;
        if (which == 2) {
            // V stored TRANSPOSED: Vt[(b*16+h)][hd][s], ld = 2048.
#pragma unroll
            for (int i = 0; i < 4; ++i)
#pragma unroll
                for (int j = 0; j < 4; ++j) {
                    const int hd = j * 16 + l15;
                    const int s4 = sbase + i * 16 + l4 * 4;
                    short4e p;
                    p[0] = (short)f2bf(acc[i][j][0]); p[1] = (short)f2bf(acc[i][j][1]);
                    p[2] = (short)f2bf(acc[i][j][2]); p[3] = (short)f2bf(acc[i][j][3]);
                    *(short4e*)(Vtws + ((size_t)(b * 16 + h) * 64 + hd) * 2048 + s4) = p;
                }
        } else {
            u16* dst = which ? Kws : Qws;
            const float qsc = which ? 1.0f : SC2;   // pre-scale Q for exp2-domain attn
#pragma unroll
            for (int i = 0; i < 4; ++i)
#pragma unroll
                for (int j = 0; j < 4; ++j)
#pragma unroll
                    for (int r = 0; r < 4; ++r) {
                        const int s = sbase + i * 16 + l4 * 4 + r;
                        dst[((size_t)(b * 16 + h) * 2048 + s) * 64 + j * 16 + l15] =
                            f2bf(acc[i][j][r] * qsc);
                    }
        }
    }
#undef GEMM_STAGE
}

// ---------------------------------------------------------------------------
// LDS-free MFMA flash attention. 1 wave per block, QBLK=32, KVBLK=64.
// KV per (b,h) = 512 KB -> L2-resident; bid%8 pins each bh to one XCD.
// Swapped QK^T: lane owns q-row q0+(lane&31); K/V^T rows are per-lane
// contiguous global loads (no cross-lane sharing -> no LDS, no barriers).
// Softmax in-register; P->A-frags via cvt_pk_bf16 + permlane32_swap (T12);
// defer-max (T13); 1/l + alpha broadcast via __shfl.
// ---------------------------------------------------------------------------
__global__ __launch_bounds__(64, 4) void attn_nolds(
    const u16* __restrict__ Qg, const u16* __restrict__ Kg,
    const u16* __restrict__ Vtg, u16* __restrict__ Og)
{
    const int lane = threadIdx.x;
    const int l31 = lane & 31, hi = lane >> 5;
    const int bid = blockIdx.x;
    const int bh = bid & 31;                 // bid%8 stable per bh -> XCD-pinned KV
    const int qchunk = 63 - (bid >> 5);      // heavy chunks dispatch first
    const int q0 = qchunk * 32;
    const int qrow = q0 + l31;

    const u16* Qp = Qg + (size_t)bh * CS * CHD;
    const u16* Kp = Kg + (size_t)bh * CS * CHD;
    const u16* Vp = Vtg + (size_t)bh * CHD * CS;

    // Q B-frags (pre-scaled by SC2 at QKV epilogue): Q[q0+l31][c*16+hi*8+j]
    short8 qf[4];
#pragma unroll
    for (int c = 0; c < 4; ++c)
        qf[c] = *(const short8*)(Qp + (size_t)qrow * 64 + c * 16 + hi * 8);

    f32x16 o0, o1;
#pragma unroll
    for (int r = 0; r < 16; ++r) { o0[r] = 0.f; o1[r] = 0.f; }
    float m_run = -1e30f, l_run = 0.f;

    const int nkt = (qchunk >> 1) + 1;

    for (int kt = 0; kt < nkt; ++kt) {
        const int k0 = kt * 64;
        const bool edge = (k0 + 63 > q0);
        const bool do_hi = (k0 + 32 <= q0 + 31);   // upper 32 k-rows not fully masked

        // ---- K frags (per-lane rows) + S^T = K*Q^T.  acc col = q = l31.
        const u16* Kb = Kp + (size_t)(k0 + l31) * 64 + hi * 8;
        f32x16 s0, s1;
#pragma unroll
        for (int r = 0; r < 16; ++r) s0[r] = 0.f;
        __builtin_amdgcn_s_setprio(1);
#pragma unroll
        for (int c = 0; c < 4; ++c) {
            const short8 kf = *(const short8*)(Kb + c * 16);
            s0 = __builtin_amdgcn_mfma_f32_32x32x16_bf16(kf, qf[c], s0, 0, 0, 0);
        }
        if (do_hi) {
#pragma unroll
            for (int r = 0; r < 16; ++r) s1[r] = 0.f;
#pragma unroll
            for (int c = 0; c < 4; ++c) {
                const short8 kf = *(const short8*)(Kb + 32 * 64 + c * 16);
                s1 = __builtin_amdgcn_mfma_f32_32x32x16_bf16(kf, qf[c], s1, 0, 0, 0);
            }
        }
        __builtin_amdgcn_s_setprio(0);

        // ---- causal mask + row max (scores already in exp2 domain)
        float pmax = -1e30f;
#pragma unroll
        for (int r = 0; r < 16; ++r) {
            float a0 = s0[r];
            if (edge) {
                const int koff = (r & 3) + 8 * (r >> 2) + 4 * hi;   // crow(r,hi)
                if (k0 + koff > qrow) a0 = -1e30f;
            }
            s0[r] = a0;
            pmax = fmaxf(pmax, a0);
        }
        if (do_hi) {
#pragma unroll
            for (int r = 0; r < 16; ++r) {
                float a1 = s1[r];
                if (edge) {
                    const int koff = (r & 3) + 8 * (r >> 2) + 4 * hi;
                    if (k0 + 32 + koff > qrow) a1 = -1e30f;
                }
                s1[r] = a1;
                pmax = fmaxf(pmax, a1);
            }
        }
        pmax = fmaxf(pmax, __shfl_xor(pmax, 32));

        // ---- defer-max rescale (rare): alpha per q-row lives in lane qq
        if (!__all(pmax - m_run <= DEFER_THR)) {
            const float mn = fmaxf(m_run, pmax);
            const float al = EXP2F(m_run - mn);
            l_run *= al;
            m_run = mn;
#pragma unroll
            for (int r = 0; r < 16; ++r) {
                const int qq = (r & 3) + 8 * (r >> 2) + 4 * hi;
                const float av = __shfl(al, qq);
                o0[r] *= av; o1[r] *= av;
            }
        }

        // ---- P = exp2(s - m), row-sum
        float lsum = 0.f;
#pragma unroll
        for (int r = 0; r < 16; ++r) {
            const float p0 = EXP2F(s0[r] - m_run);
            s0[r] = p0; lsum += p0;
        }
        if (do_hi) {
#pragma unroll
            for (int r = 0; r < 16; ++r) {
                const float p1 = EXP2F(s1[r] - m_run);
                s1[r] = p1; lsum += p1;
            }
        }
        lsum += __shfl_xor(lsum, 32);
        l_run += lsum;

        // ---- P -> A-frags in-register (T12) + PV from per-lane V^T rows
        const u16* Vb  = Vp + (size_t)l31 * CS + k0 + hi * 8;
        const u16* Vb2 = Vb + (size_t)32 * CS;
#define PV_STEP(KS, SV)                                                          \
        {                                                                        \
            const int rb = ((KS) & 1) * 8;                                       \
            u32 w0 = pkbf(SV[rb + 0], SV[rb + 1]);                               \
            u32 w1 = pkbf(SV[rb + 2], SV[rb + 3]);                               \
            u32 w2 = pkbf(SV[rb + 4], SV[rb + 5]);                               \
            u32 w3 = pkbf(SV[rb + 6], SV[rb + 7]);                               \
            asm("v_permlane32_swap_b32 %0, %1" : "+v"(w0), "+v"(w2));            \
            asm("v_permlane32_swap_b32 %0, %1" : "+v"(w1), "+v"(w3));            \
            union { u32 uw[4]; short8 v; } pu;                                   \
            pu.uw[0] = w0; pu.uw[1] = w1; pu.uw[2] = w2; pu.uw[3] = w3;          \
            const short8 pa = pu.v;                                              \
            const short8 v0 = *(const short8*)(Vb  + (KS) * 16);                 \
            const short8 v1 = *(const short8*)(Vb2 + (KS) * 16);                 \
            __builtin_amdgcn_s_setprio(1);                                       \
            o0 = __builtin_amdgcn_mfma_f32_32x32x16_bf16(pa, v0, o0, 0, 0, 0);   \
            o1 = __builtin_amdgcn_mfma_f32_32x32x16_bf16(pa, v1, o1, 0, 0, 0);   \
            __builtin_amdgcn_s_setprio(0);                                       \
        }
        PV_STEP(0, s0)
        PV_STEP(1, s0)
        if (do_hi) {
            PV_STEP(2, s1)
            PV_STEP(3, s1)
        }
#undef PV_STEP
    }

    // ---- normalize (1/l via shfl) + store O bf16 in [B][S][D]
    const float invl = 1.f / l_run;
    const int b = bh >> 4, h = bh & 15;
#pragma unroll
    for (int g = 0; g < 4; ++g)
#pragma unroll
        for (int c = 0; c < 4; ++c) {
            const int qq = 8 * g + 4 * hi + c;       // crow(4g+c, hi)
            const float av = __shfl(invl, qq);
            u16* dst = Og + ((size_t)(b * CS + q0 + qq)) * CD + h * 64 + l31;
            dst[0]  = f2bf(o0[g * 4 + c] * av);
            dst[32] = f2bf(o1[g * 4 + c] * av);
        }
}

// ---------------------------------------------------------------------------
extern "C" void kernel_launch(void* const* d_in, const int* in_sizes, int n_in,
                              void* d_out, int out_size, void* d_ws, size_t ws_size,
                              hipStream_t stream)
{
    const float* x     = (const float*)d_in[0];   // (B,S,D)
    const float* w_qkv = (const float*)d_in[1];   // (D,3D)
    const float* w_out = (const float*)d_in[2];   // (D,D)
    float* out = (float*)d_out;                   // (B,S,D) f32

    u16* xb    = (u16*)d_ws;                      // [4096][1024]
    u16* wqkvT = xb    + (size_t)4096 * 1024;     // [3072][1024]
    u16* woutT = wqkvT + (size_t)3072 * 1024;     // [1024][1024]
    u16* Qws   = woutT + (size_t)1024 * 1024;     // [32][2048][64]  (SC2-scaled)
    u16* Kws   = Qws   + (size_t)32 * 2048 * 64;
    u16* Vtws  = Kws   + (size_t)32 * 2048 * 64;  // [32][64][2048]
    u16* Ob    = Vtws  + (size_t)32 * 2048 * 64;  // [4096][1024]

    cvt_x<<<2048, 256, 0, stream>>>(x, xb);
    txw<<<dim3(48, 16), 256, 0, stream>>>(w_qkv, wqkvT, 3072);
    txw<<<dim3(16, 16), 256, 0, stream>>>(w_out, woutT, 1024);

    gemm_mfma<<<dim3(24, 32), 256, 0, stream>>>(xb, wqkvT, 0, Qws, Kws, Vtws, nullptr);
    attn_nolds<<<2048, 64, 0, stream>>>(Qws, Kws, Vtws, Ob);
    gemm_mfma<<<dim3(8, 32), 256, 0, stream>>>(Ob, woutT, 1, nullptr, nullptr, nullptr, out);
}

// Round 6
// 225.021 us; speedup vs baseline: 1.0354x; 1.0354x over previous
//
#include <hip/hip_runtime.h>
#include <hip/hip_bf16.h>
#include <stdint.h>

typedef unsigned short u16;
typedef unsigned int u32;
typedef __attribute__((ext_vector_type(8))) short short8;    // 8 bf16 = 4 VGPR (MFMA A/B frag)
typedef __attribute__((ext_vector_type(4))) short short4e;   // 8B packed store
typedef __attribute__((ext_vector_type(4))) float f32x4;     // 16x16 MFMA C/D frag
typedef __attribute__((ext_vector_type(16))) float f32x16;   // 32x32 MFMA C/D frag

constexpr int CB = 2, CS = 2048, CD = 1024, CH = 16, CHD = 64;
constexpr float SC2 = 0.125f * 1.44269504088896f;   // scale * log2(e): exp2 domain
constexpr float DEFER_THR = 11.0f;                  // P bounded by 2^11

__device__ __forceinline__ u16 f2bf(float f) {
    unsigned u = __float_as_uint(f);
    u += 0x7fffu + ((u >> 16) & 1u);     // RNE
    return (u16)(u >> 16);
}
__device__ __forceinline__ float bf2f(short s) {
    return __uint_as_float(((u32)(unsigned short)s) << 16);
}

#if __has_builtin(__builtin_amdgcn_exp2f)
#define EXP2F(x) __builtin_amdgcn_exp2f(x)
#else
#define EXP2F(x) exp2f(x)
#endif

// pack two f32 -> u32 of 2 bf16 (lo = a, hi = b)
__device__ __forceinline__ u32 pkbf(float a, float b) {
    u32 r;
    asm("v_cvt_pk_bf16_f32 %0, %1, %2" : "=v"(r) : "v"(a), "v"(b));
    return r;
}

// ---------------------------------------------------------------------------
// f32 -> bf16 elementwise (x). 8 elems/thread, exact grid.
// ---------------------------------------------------------------------------
__global__ __launch_bounds__(256) void cvt_x(const float* __restrict__ X, u16* __restrict__ Y) {
    const int i = (blockIdx.x * 256 + threadIdx.x) * 8;
    const float4 v0 = *(const float4*)(X + i);
    const float4 v1 = *(const float4*)(X + i + 4);
    short8 r;
    r[0] = (short)f2bf(v0.x); r[1] = (short)f2bf(v0.y);
    r[2] = (short)f2bf(v0.z); r[3] = (short)f2bf(v0.w);
    r[4] = (short)f2bf(v1.x); r[5] = (short)f2bf(v1.y);
    r[6] = (short)f2bf(v1.z); r[7] = (short)f2bf(v1.w);
    *(short8*)(Y + i) = r;
}

// ---------------------------------------------------------------------------
// Transpose + convert: W [1024][N] f32  ->  Bt [N][1024] bf16.  64x64 tiles.
// ---------------------------------------------------------------------------
__global__ __launch_bounds__(256) void txw(const float* __restrict__ W, u16* __restrict__ Bt,
                                           int ldw) {
    __shared__ u16 T[64][80];
    const int t = threadIdx.x;
    const int n0 = blockIdx.x * 64, k0 = blockIdx.y * 64;
    const int r = t >> 4, c4 = (t & 15) * 4;
#pragma unroll
    for (int p = 0; p < 4; ++p) {
        const int kr = r + p * 16;
        const float4 v = *(const float4*)(W + (size_t)(k0 + kr) * ldw + n0 + c4);
        T[c4 + 0][kr] = f2bf(v.x); T[c4 + 1][kr] = f2bf(v.y);
        T[c4 + 2][kr] = f2bf(v.z); T[c4 + 3][kr] = f2bf(v.w);
    }
    __syncthreads();
    const int rr = t >> 2, cc = (t & 3) * 16;
    const short8 a = *(const short8*)((const char*)&T[0][0] + rr * 160 + cc * 2);
    const short8 b = *(const short8*)((const char*)&T[0][0] + rr * 160 + cc * 2 + 16);
    u16* dst = Bt + (size_t)(n0 + rr) * 1024 + k0 + cc;
    *(short8*)dst = a;
    *(short8*)(dst + 8) = b;
}

// ---------------------------------------------------------------------------
// bf16 MFMA GEMM, 128x128 tile, BK=32, 4 waves (2x2), double-buffered LDS,
// async global_load_lds (width 16) staging, 1 barrier per K-step.  K = 1024.
// mode 0: scatter QKV per head; Q pre-scaled by SC2. mode 1: f32 write.
// ---------------------------------------------------------------------------
__global__ __launch_bounds__(256) void gemm_mfma(
    const u16* __restrict__ A, const u16* __restrict__ Bt, int mode,
    u16* __restrict__ Qws, u16* __restrict__ Kws, u16* __restrict__ Vtws,
    float* __restrict__ Cf)
{
    __shared__ u16 SB[2][8192];
    const int tid = threadIdx.x;
    const int w = tid >> 6, lane = tid & 63;
    const int l15 = lane & 15, l4 = lane >> 4;
    const int wr = w >> 1, wc = w & 1;
    const int n0 = blockIdx.x * 128, m0 = blockIdx.y * 128;

    f32x4 acc[4][4];
    const f32x4 zf = {0.f, 0.f, 0.f, 0.f};
#pragma unroll
    for (int i = 0; i < 4; ++i)
#pragma unroll
        for (int j = 0; j < 4; ++j) acc[i][j] = zf;

#define GEMM_STAGE(BUF, K0)                                                     \
    {                                                                           \
        _Pragma("unroll")                                                       \
        for (int it = 0; it < 4; ++it) {                                        \
            const int c = tid + it * 256;                                       \
            const u16* src;                                                     \
            if (c < 512) { const int row = c >> 2, cs = c & 3;                  \
                src = A + (size_t)(m0 + row) * 1024 + (K0) + cs * 8; }          \
            else { const int c2 = c - 512; const int row = c2 >> 2, cs = c2 & 3;\
                src = Bt + (size_t)(n0 + row) * 1024 + (K0) + cs * 8; }         \
            __builtin_amdgcn_global_load_lds(                                   \
                (const __attribute__((address_space(1))) unsigned int*)src,     \
                (__attribute__((address_space(3))) unsigned int*)&SB[BUF][c*8], \
                16, 0, 0);                                                      \
        }                                                                       \
    }

    GEMM_STAGE(0, 0);
    __syncthreads();

    for (int t = 0; t < 32; ++t) {
        const int cur = t & 1;
        if (t < 31) GEMM_STAGE(cur ^ 1, (t + 1) * 32);

        const u16* Al = &SB[cur][0];
        const u16* Bl = &SB[cur][4096];
        short8 a[4], b[4];
#pragma unroll
        for (int i = 0; i < 4; ++i)
            a[i] = *(const short8*)(Al + (wr * 64 + i * 16 + l15) * 32 + l4 * 8);
#pragma unroll
        for (int j = 0; j < 4; ++j)
            b[j] = *(const short8*)(Bl + (wc * 64 + j * 16 + l15) * 32 + l4 * 8);
        __builtin_amdgcn_s_setprio(1);
#pragma unroll
        for (int i = 0; i < 4; ++i)
#pragma unroll
            for (int j = 0; j < 4; ++j)
                acc[i][j] = __builtin_amdgcn_mfma_f32_16x16x32_bf16(a[i], b[j], acc[i][j], 0, 0, 0);
        __builtin_amdgcn_s_setprio(0);
        __syncthreads();
    }

    // C/D layout (16x16): col = lane&15, row = (lane>>4)*4 + reg.
    if (mode == 1) {
#pragma unroll
        for (int i = 0; i < 4; ++i)
#pragma unroll
            for (int j = 0; j < 4; ++j)
#pragma unroll
                for (int r = 0; r < 4; ++r)
                    Cf[(size_t)(m0 + wr * 64 + i * 16 + l4 * 4 + r) * 1024 +
                       n0 + wc * 64 + j * 16 + l15] = acc[i][j][r];
    } else {
        const int e0 = n0 + wc * 64;
        const int which = e0 >> 10;
        const int h = (e0 >> 6) & 15;
        const int b = m0 >> 11;
        const int sbase = (m0 & 2047) + wr * 64;
        if (which == 2) {
            // V stored TRANSPOSED: Vt[(b*16+h)][hd][s], ld = 2048.
#pragma unroll
            for (int i = 0; i < 4; ++i)
#pragma unroll
                for (int j = 0; j < 4; ++j) {
                    const int hd = j * 16 + l15;
                    const int s4 = sbase + i * 16 + l4 * 4;
                    short4e p;
                    p[0] = (short)f2bf(acc[i][j][0]); p[1] = (short)f2bf(acc[i][j][1]);
                    p[2] = (short)f2bf(acc[i][j][2]); p[3] = (short)f2bf(acc[i][j][3]);
                    *(short4e*)(Vtws + ((size_t)(b * 16 + h) * 64 + hd) * 2048 + s4) = p;
                }
        } else {
            u16* dst = which ? Kws : Qws;
            const float qsc = which ? 1.0f : SC2;   // pre-scale Q for exp2-domain attn
#pragma unroll
            for (int i = 0; i < 4; ++i)
#pragma unroll
                for (int j = 0; j < 4; ++j)
#pragma unroll
                    for (int r = 0; r < 4; ++r) {
                        const int s = sbase + i * 16 + l4 * 4 + r;
                        dst[((size_t)(b * 16 + h) * 2048 + s) * 64 + j * 16 + l15] =
                            f2bf(acc[i][j][r] * qsc);
                    }
        }
    }
#undef GEMM_STAGE
}

// ---------------------------------------------------------------------------
// K-SPLIT MFMA flash attention (round-3 LDS body + flash-decode K split).
// Block = (bh, jt=q-block-of-128, seg of <=8 k-tiles64).  4 waves x 32 q.
// Per bh: jt 0..15, segs(jt)=ceil((jt+1)/4) -> 40 blocks; grid 1280, 5120
// waves (20/CU supply vs old 8/CU).  jt<4: single seg -> final write.
// jt>=4: write bf16 partial (O, m, l); combine kernel merges <=4 partials.
// ---------------------------------------------------------------------------
__global__ __launch_bounds__(256, 4) void attn_seg(
    const u16* __restrict__ Qg, const u16* __restrict__ Kg,
    const u16* __restrict__ Vtg, u16* __restrict__ Og,
    u16* __restrict__ Opart, float* __restrict__ Oml)
{
    __shared__ u16 KV[2][8192];    // per buffer: K[64][64] | V^T[64][64], XOR-swizzled

    static const int jt_of_u[40] = {0,1,2,3, 4,4, 5,5, 6,6, 7,7,
                                    8,8,8, 9,9,9, 10,10,10, 11,11,11,
                                    12,12,12,12, 13,13,13,13, 14,14,14,14, 15,15,15,15};
    static const int seg_of_u[40] = {0,0,0,0, 0,1, 0,1, 0,1, 0,1,
                                     0,1,2, 0,1,2, 0,1,2, 0,1,2,
                                     0,1,2,3, 0,1,2,3, 0,1,2,3, 0,1,2,3};

    const int tid = threadIdx.x;
    const int w = tid >> 6, lane = tid & 63;
    const int l31 = lane & 31, hi = lane >> 5;
    const int bid = blockIdx.x;
    const int u = 39 - (bid >> 5);          // heavy (jt=15) blocks dispatch first
    const int bh = bid & 31;                // bh%8 stable -> XCD-local KV reuse
    const int jt = jt_of_u[u], seg = seg_of_u[u];
    const int t0 = seg * 8;
    const int tmax = 2 * jt + 2;
    const int t1 = (tmax < t0 + 8) ? tmax : (t0 + 8);

    const u16* Qp = Qg + (size_t)bh * CS * CHD;
    const u16* Kp = Kg + (size_t)bh * CS * CHD;
    const u16* Vp = Vtg + (size_t)bh * CHD * CS;
    const int q0w = jt * 128 + w * 32;
    const int qrow = q0w + l31;

    // Q B-frags (pre-scaled by SC2): Q[qrow][c*16 + hi*8 + j]
    short8 qf[4];
#pragma unroll
    for (int c = 0; c < 4; ++c)
        qf[c] = *(const short8*)(Qp + (size_t)qrow * 64 + c * 16 + hi * 8);

    f32x16 o0, o1;
#pragma unroll
    for (int r = 0; r < 16; ++r) { o0[r] = 0.f; o1[r] = 0.f; }
    float m_run = -1e30f, l_run = 0.f;

    short8 stg[4];
#define ATTN_ISSUE(K0)                                                           \
    {                                                                            \
        _Pragma("unroll")                                                        \
        for (int it = 0; it < 4; ++it) {                                         \
            const int c = tid + it * 256;                                        \
            const int ob = c * 16;                                               \
            const u16* src;                                                      \
            if (ob < 8192) { const int row = ob >> 7, cs = (ob >> 4) & 7;        \
                src = Kp + (size_t)((K0) + row) * 64 + cs * 8; }                 \
            else { const int o2 = ob - 8192; const int row = o2 >> 7,            \
                cs = (o2 >> 4) & 7;                                              \
                src = Vp + (size_t)row * CS + (K0) + cs * 8; }                   \
            stg[it] = *(const short8*)src;                                       \
        }                                                                        \
    }
#define ATTN_WRITE(BUF)                                                          \
    {                                                                            \
        _Pragma("unroll")                                                        \
        for (int it = 0; it < 4; ++it) {                                         \
            const int c = tid + it * 256;                                        \
            const int ob = c * 16;                                               \
            int db;                                                              \
            if (ob < 8192) { const int row = ob >> 7; db = ob ^ ((row & 7) << 4); } \
            else { const int o2 = ob - 8192; const int row = o2 >> 7;            \
                db = 8192 + (o2 ^ ((row & 7) << 4)); }                           \
            *(short8*)((char*)&KV[BUF][0] + db) = stg[it];                       \
        }                                                                        \
    }

    ATTN_ISSUE(t0 * 64);
    ATTN_WRITE(0);
    __syncthreads();

    for (int kt = t0; kt < t1; ++kt) {
        const int k0 = kt * 64;
        const int cur = (kt - t0) & 1;
        if (kt + 1 < t1) ATTN_ISSUE((kt + 1) * 64);

        if (k0 <= q0w + 31) {
            const char* Kl = (const char*)&KV[cur][0];
            const char* Vl = (const char*)&KV[cur][4096];
            const bool edge = (k0 + 63 > q0w);
            const bool do_hi = (k0 + 32 <= q0w + 31);

            // ---- S^T = K * Q^T : lane owns q-col = l31 (verified 32x32 C layout)
            f32x16 s0, s1;
#pragma unroll
            for (int r = 0; r < 16; ++r) s0[r] = 0.f;
            __builtin_amdgcn_s_setprio(1);
#pragma unroll
            for (int c = 0; c < 4; ++c) {
                const int row = l31;
                const short8 kf = *(const short8*)(Kl + row * 128 +
                                    ((c * 32 + hi * 16) ^ ((row & 7) << 4)));
                s0 = __builtin_amdgcn_mfma_f32_32x32x16_bf16(kf, qf[c], s0, 0, 0, 0);
            }
            if (do_hi) {
#pragma unroll
                for (int r = 0; r < 16; ++r) s1[r] = 0.f;
#pragma unroll
                for (int c = 0; c < 4; ++c) {
                    const int row = 32 + l31;
                    const short8 kf = *(const short8*)(Kl + row * 128 +
                                        ((c * 32 + hi * 16) ^ ((row & 7) << 4)));
                    s1 = __builtin_amdgcn_mfma_f32_32x32x16_bf16(kf, qf[c], s1, 0, 0, 0);
                }
            }
            __builtin_amdgcn_s_setprio(0);

            // ---- causal mask + row max (scores already exp2-domain scaled)
            float pmax = -1e30f;
#pragma unroll
            for (int r = 0; r < 16; ++r) {
                float a0 = s0[r];
                if (edge) {
                    const int koff = (r & 3) + 8 * (r >> 2) + 4 * hi;   // crow(r,hi)
                    if (k0 + koff > qrow) a0 = -1e30f;
                }
                s0[r] = a0;
                pmax = fmaxf(pmax, a0);
            }
            if (do_hi) {
#pragma unroll
                for (int r = 0; r < 16; ++r) {
                    float a1 = s1[r];
                    if (edge) {
                        const int koff = (r & 3) + 8 * (r >> 2) + 4 * hi;
                        if (k0 + 32 + koff > qrow) a1 = -1e30f;
                    }
                    s1[r] = a1;
                    pmax = fmaxf(pmax, a1);
                }
            }
            pmax = fmaxf(pmax, __shfl_xor(pmax, 32));

            // ---- defer-max rescale (rare)
            if (!__all(pmax - m_run <= DEFER_THR)) {
                const float mn = fmaxf(m_run, pmax);
                const float al = EXP2F(m_run - mn);
                l_run *= al;
                m_run = mn;
#pragma unroll
                for (int r = 0; r < 16; ++r) {
                    const int qq = (r & 3) + 8 * (r >> 2) + 4 * hi;
                    const float av = __shfl(al, qq);
                    o0[r] *= av; o1[r] *= av;
                }
            }

            // ---- P = exp2(s - m), row-sum
            float lsum = 0.f;
#pragma unroll
            for (int r = 0; r < 16; ++r) {
                const float p0 = EXP2F(s0[r] - m_run);
                s0[r] = p0; lsum += p0;
            }
            if (do_hi) {
#pragma unroll
                for (int r = 0; r < 16; ++r) {
                    const float p1 = EXP2F(s1[r] - m_run);
                    s1[r] = p1; lsum += p1;
                }
            }
            lsum += __shfl_xor(lsum, 32);
            l_run += lsum;

            // ---- P -> A-frags in-register (T12) + PV from swizzled LDS V^T
#define PV_STEP(KS, SV)                                                          \
            {                                                                    \
                const int rb = ((KS) & 1) * 8;                                   \
                u32 w0 = pkbf(SV[rb + 0], SV[rb + 1]);                           \
                u32 w1 = pkbf(SV[rb + 2], SV[rb + 3]);                           \
                u32 w2 = pkbf(SV[rb + 4], SV[rb + 5]);                           \
                u32 w3 = pkbf(SV[rb + 6], SV[rb + 7]);                           \
                asm("v_permlane32_swap_b32 %0, %1" : "+v"(w0), "+v"(w2));        \
                asm("v_permlane32_swap_b32 %0, %1" : "+v"(w1), "+v"(w3));        \
                union { u32 uw[4]; short8 v; } pu;                               \
                pu.uw[0] = w0; pu.uw[1] = w1; pu.uw[2] = w2; pu.uw[3] = w3;      \
                const short8 pa = pu.v;                                          \
                const int vr0 = l31, vr1 = 32 + l31;                             \
                const short8 v0 = *(const short8*)(Vl + vr0 * 128 +              \
                                    (((KS) * 32 + hi * 16) ^ ((vr0 & 7) << 4))); \
                const short8 v1 = *(const short8*)(Vl + vr1 * 128 +              \
                                    (((KS) * 32 + hi * 16) ^ ((vr1 & 7) << 4))); \
                __builtin_amdgcn_s_setprio(1);                                   \
                o0 = __builtin_amdgcn_mfma_f32_32x32x16_bf16(pa, v0, o0, 0, 0, 0);\
                o1 = __builtin_amdgcn_mfma_f32_32x32x16_bf16(pa, v1, o1, 0, 0, 0);\
                __builtin_amdgcn_s_setprio(0);                                   \
            }
            PV_STEP(0, s0)
            PV_STEP(1, s0)
            if (do_hi) {
                PV_STEP(2, s1)
                PV_STEP(3, s1)
            }
#undef PV_STEP
        }

        if (kt + 1 < t1) ATTN_WRITE(cur ^ 1);
        __syncthreads();
    }

    if (jt < 4) {
        // single segment: normalize + final store to [B][S][D]
        const float invl = 1.f / l_run;
        const int b = bh >> 4, h = bh & 15;
#pragma unroll
        for (int g = 0; g < 4; ++g)
#pragma unroll
            for (int c = 0; c < 4; ++c) {
                const int qq = 8 * g + 4 * hi + c;       // crow(4g+c, hi)
                const float av = __shfl(invl, qq);
                u16* dst = Og + ((size_t)(bh >> 4) * CS + jt * 128 + w * 32 + qq) * CD
                             + (bh & 15) * 64 + l31;
                dst[0]  = f2bf(o0[g * 4 + c] * av);
                dst[32] = f2bf(o1[g * 4 + c] * av);
            }
        (void)0;
    } else {
        // partial store: slot = bh*36 + (u-4); rows w*32..+31, unnormalized
        const int slot = bh * 36 + (u - 4);
        u16* pd = Opart + ((size_t)slot * 128 + w * 32) * 64;
#pragma unroll
        for (int g = 0; g < 4; ++g)
#pragma unroll
            for (int c = 0; c < 4; ++c) {
                const int qq = 8 * g + 4 * hi + c;
                pd[qq * 64 + l31]      = f2bf(o0[g * 4 + c]);
                pd[qq * 64 + 32 + l31] = f2bf(o1[g * 4 + c]);
            }
        if (lane < 32) {
            const size_t mi = ((size_t)slot * 128 + w * 32 + l31) * 2;
            Oml[mi]     = m_run;
            Oml[mi + 1] = l_run;
        }
    }
#undef ATTN_ISSUE
#undef ATTN_WRITE
}

// ---------------------------------------------------------------------------
// Combine <=4 K-split partials per q-row (jt>=4 only).  Memory-bound.
// Block = (jt-4, bh); thread t: row = t>>1, cols = (t&1)*32..+31.
// ---------------------------------------------------------------------------
__global__ __launch_bounds__(256) void attn_combine(
    const u16* __restrict__ Opart, const float* __restrict__ Oml,
    u16* __restrict__ Og)
{
    static const int ub[16] = {0,1,2,3,4,6,8,10,12,15,18,21,24,28,32,36};
    const int jt = 4 + blockIdx.x;
    const int bh = blockIdx.y;
    const int tid = threadIdx.x;
    const int r = tid >> 1, half = tid & 1;
    const int segs = (jt + 4) >> 2;          // ceil((jt+1)/4)
    const int slot0 = bh * 36 + ub[jt] - 4;

    float acc[32];
#pragma unroll
    for (int k = 0; k < 32; ++k) acc[k] = 0.f;
    float M = -1e30f, L = 0.f;

    for (int i = 0; i < segs; ++i) {
        const int slot = slot0 + i;
        const float mi = Oml[((size_t)slot * 128 + r) * 2];
        const float li = Oml[((size_t)slot * 128 + r) * 2 + 1];
        float wi;
        if (mi > M) {
            const float sc = EXP2F(M - mi);
#pragma unroll
            for (int k = 0; k < 32; ++k) acc[k] *= sc;
            L *= sc; M = mi; wi = 1.f;
        } else {
            wi = EXP2F(mi - M);
        }
        const u16* op = Opart + ((size_t)slot * 128 + r) * 64 + half * 32;
#pragma unroll
        for (int v = 0; v < 4; ++v) {
            const short8 x = *(const short8*)(op + v * 8);
#pragma unroll
            for (int e = 0; e < 8; ++e)
                acc[v * 8 + e] += wi * bf2f(x[e]);
        }
        L += wi * li;
    }

    const float inv = 1.f / L;
    const int b = bh >> 4, h = bh & 15;
    const int q = jt * 128 + r;
    u16* dst = Og + ((size_t)(b * CS + q)) * CD + h * 64 + half * 32;
#pragma unroll
    for (int v = 0; v < 4; ++v) {
        short8 y;
#pragma unroll
        for (int e = 0; e < 8; ++e) y[e] = (short)f2bf(acc[v * 8 + e] * inv);
        *(short8*)(dst + v * 8) = y;
    }
}

// ---------------------------------------------------------------------------
extern "C" void kernel_launch(void* const* d_in, const int* in_sizes, int n_in,
                              void* d_out, int out_size, void* d_ws, size_t ws_size,
                              hipStream_t stream)
{
    const float* x     = (const float*)d_in[0];   // (B,S,D)
    const float* w_qkv = (const float*)d_in[1];   // (D,3D)
    const float* w_out = (const float*)d_in[2];   // (D,D)
    float* out = (float*)d_out;                   // (B,S,D) f32

    u16* xb    = (u16*)d_ws;                      // [4096][1024]
    u16* wqkvT = xb    + (size_t)4096 * 1024;     // [3072][1024]
    u16* woutT = wqkvT + (size_t)3072 * 1024;     // [1024][1024]
    u16* Qws   = woutT + (size_t)1024 * 1024;     // [32][2048][64]  (SC2-scaled)
    u16* Kws   = Qws   + (size_t)32 * 2048 * 64;
    u16* Vtws  = Kws   + (size_t)32 * 2048 * 64;  // [32][64][2048]
    u16* Ob    = Vtws  + (size_t)32 * 2048 * 64;  // [4096][1024] bf16
    u16* Opart = Ob    + (size_t)4096 * 1024;     // [1152][128][64] bf16 partials
    float* Oml = (float*)(Opart + (size_t)1152 * 128 * 64);  // [1152][128][2] f32

    cvt_x<<<2048, 256, 0, stream>>>(x, xb);
    txw<<<dim3(48, 16), 256, 0, stream>>>(w_qkv, wqkvT, 3072);
    txw<<<dim3(16, 16), 256, 0, stream>>>(w_out, woutT, 1024);

    gemm_mfma<<<dim3(24, 32), 256, 0, stream>>>(xb, wqkvT, 0, Qws, Kws, Vtws, nullptr);
    attn_seg<<<1280, 256, 0, stream>>>(Qws, Kws, Vtws, Ob, Opart, Oml);
    attn_combine<<<dim3(12, 32), 256, 0, stream>>>(Opart, Oml, Ob);
    gemm_mfma<<<dim3(8, 32), 256, 0, stream>>>(Ob, woutT, 1, nullptr, nullptr, nullptr, out);
}

// Round 7
// 201.723 us; speedup vs baseline: 1.1550x; 1.1155x over previous
//
#include <hip/hip_runtime.h>
#include <hip/hip_bf16.h>
#include <stdint.h>

typedef unsigned short u16;
typedef unsigned int u32;
typedef __attribute__((ext_vector_type(8))) short short8;    // 8 bf16 = 4 VGPR (MFMA A/B frag)
typedef __attribute__((ext_vector_type(4))) short short4e;   // 8B packed store
typedef __attribute__((ext_vector_type(4))) float f32x4;     // 16x16 MFMA C/D frag
typedef __attribute__((ext_vector_type(16))) float f32x16;   // 32x32 MFMA C/D frag

constexpr int CB = 2, CS = 2048, CD = 1024, CH = 16, CHD = 64;
constexpr float SC2 = 0.125f * 1.44269504088896f;   // scale * log2(e): exp2 domain
constexpr float DEFER_THR = 11.0f;                  // P bounded by 2^11

__device__ __forceinline__ u16 f2bf(float f) {
    unsigned u = __float_as_uint(f);
    u += 0x7fffu + ((u >> 16) & 1u);     // RNE
    return (u16)(u >> 16);
}
__device__ __forceinline__ float bf2f(short s) {
    return __uint_as_float(((u32)(unsigned short)s) << 16);
}

#if __has_builtin(__builtin_amdgcn_exp2f)
#define EXP2F(x) __builtin_amdgcn_exp2f(x)
#else
#define EXP2F(x) exp2f(x)
#endif

// pack two f32 -> u32 of 2 bf16 (lo = a, hi = b)
__device__ __forceinline__ u32 pkbf(float a, float b) {
    u32 r;
    asm("v_cvt_pk_bf16_f32 %0, %1, %2" : "=v"(r) : "v"(a), "v"(b));
    return r;
}

// ---------------------------------------------------------------------------
// f32 -> bf16 elementwise (x). 8 elems/thread, exact grid.
// ---------------------------------------------------------------------------
__global__ __launch_bounds__(256) void cvt_x(const float* __restrict__ X, u16* __restrict__ Y) {
    const int i = (blockIdx.x * 256 + threadIdx.x) * 8;
    const float4 v0 = *(const float4*)(X + i);
    const float4 v1 = *(const float4*)(X + i + 4);
    short8 r;
    r[0] = (short)f2bf(v0.x); r[1] = (short)f2bf(v0.y);
    r[2] = (short)f2bf(v0.z); r[3] = (short)f2bf(v0.w);
    r[4] = (short)f2bf(v1.x); r[5] = (short)f2bf(v1.y);
    r[6] = (short)f2bf(v1.z); r[7] = (short)f2bf(v1.w);
    *(short8*)(Y + i) = r;
}

// ---------------------------------------------------------------------------
// Transpose + convert: W [1024][N] f32  ->  Bt [N][1024] bf16.  64x64 tiles.
// ---------------------------------------------------------------------------
__global__ __launch_bounds__(256) void txw(const float* __restrict__ W, u16* __restrict__ Bt,
                                           int ldw) {
    __shared__ u16 T[64][80];
    const int t = threadIdx.x;
    const int n0 = blockIdx.x * 64, k0 = blockIdx.y * 64;
    const int r = t >> 4, c4 = (t & 15) * 4;
#pragma unroll
    for (int p = 0; p < 4; ++p) {
        const int kr = r + p * 16;
        const float4 v = *(const float4*)(W + (size_t)(k0 + kr) * ldw + n0 + c4);
        T[c4 + 0][kr] = f2bf(v.x); T[c4 + 1][kr] = f2bf(v.y);
        T[c4 + 2][kr] = f2bf(v.z); T[c4 + 3][kr] = f2bf(v.w);
    }
    __syncthreads();
    const int rr = t >> 2, cc = (t & 3) * 16;
    const short8 a = *(const short8*)((const char*)&T[0][0] + rr * 160 + cc * 2);
    const short8 b = *(const short8*)((const char*)&T[0][0] + rr * 160 + cc * 2 + 16);
    u16* dst = Bt + (size_t)(n0 + rr) * 1024 + k0 + cc;
    *(short8*)dst = a;
    *(short8*)(dst + 8) = b;
}

// ---------------------------------------------------------------------------
// bf16 MFMA GEMM, 128x128 tile, BK=32, 4 waves (2x2), double-buffered LDS,
// async global_load_lds (width 16) staging, 1 barrier per K-step.  K = 1024.
// mode 0: scatter QKV per head (Q pre-scaled by SC2); Q/K epilogue routed
// through LDS for coalesced 16B stores.  mode 1: f32 direct write.
// ---------------------------------------------------------------------------
__global__ __launch_bounds__(256) void gemm_mfma(
    const u16* __restrict__ A, const u16* __restrict__ Bt, int mode,
    u16* __restrict__ Qws, u16* __restrict__ Kws, u16* __restrict__ Vtws,
    float* __restrict__ Cf)
{
    __shared__ u16 SB[2][8704];   // main loop uses [0..8191]; epilogue reuses all
    const int tid = threadIdx.x;
    const int w = tid >> 6, lane = tid & 63;
    const int l15 = lane & 15, l4 = lane >> 4;
    const int wr = w >> 1, wc = w & 1;
    const int n0 = blockIdx.x * 128, m0 = blockIdx.y * 128;

    f32x4 acc[4][4];
    const f32x4 zf = {0.f, 0.f, 0.f, 0.f};
#pragma unroll
    for (int i = 0; i < 4; ++i)
#pragma unroll
        for (int j = 0; j < 4; ++j) acc[i][j] = zf;

#define GEMM_STAGE(BUF, K0)                                                     \
    {                                                                           \
        _Pragma("unroll")                                                       \
        for (int it = 0; it < 4; ++it) {                                        \
            const int c = tid + it * 256;                                       \
            const u16* src;                                                     \
            if (c < 512) { const int row = c >> 2, cs = c & 3;                  \
                src = A + (size_t)(m0 + row) * 1024 + (K0) + cs * 8; }          \
            else { const int c2 = c - 512; const int row = c2 >> 2, cs = c2 & 3;\
                src = Bt + (size_t)(n0 + row) * 1024 + (K0) + cs * 8; }         \
            __builtin_amdgcn_global_load_lds(                                   \
                (const __attribute__((address_space(1))) unsigned int*)src,     \
                (__attribute__((address_space(3))) unsigned int*)&SB[BUF][c*8], \
                16, 0, 0);                                                      \
        }                                                                       \
    }

    GEMM_STAGE(0, 0);
    __syncthreads();

    for (int t = 0; t < 32; ++t) {
        const int cur = t & 1;
        if (t < 31) GEMM_STAGE(cur ^ 1, (t + 1) * 32);

        const u16* Al = &SB[cur][0];
        const u16* Bl = &SB[cur][4096];
        short8 a[4], b[4];
#pragma unroll
        for (int i = 0; i < 4; ++i)
            a[i] = *(const short8*)(Al + (wr * 64 + i * 16 + l15) * 32 + l4 * 8);
#pragma unroll
        for (int j = 0; j < 4; ++j)
            b[j] = *(const short8*)(Bl + (wc * 64 + j * 16 + l15) * 32 + l4 * 8);
        __builtin_amdgcn_s_setprio(1);
#pragma unroll
        for (int i = 0; i < 4; ++i)
#pragma unroll
            for (int j = 0; j < 4; ++j)
                acc[i][j] = __builtin_amdgcn_mfma_f32_16x16x32_bf16(a[i], b[j], acc[i][j], 0, 0, 0);
        __builtin_amdgcn_s_setprio(0);
        __syncthreads();
    }

    // C/D layout (16x16): col = lane&15, row = (lane>>4)*4 + reg.
    if (mode == 1) {
#pragma unroll
        for (int i = 0; i < 4; ++i)
#pragma unroll
            for (int j = 0; j < 4; ++j)
#pragma unroll
                for (int r = 0; r < 4; ++r)
                    Cf[(size_t)(m0 + wr * 64 + i * 16 + l4 * 4 + r) * 1024 +
                       n0 + wc * 64 + j * 16 + l15] = acc[i][j][r];
    } else {
        // which is block-uniform (n0 is a multiple of 128).
        const int which = n0 >> 10;           // 0=q 1=k 2=v
        const int b = m0 >> 11;
        const int sbase = m0 & 2047;
        if (which == 2) {
            // V stored TRANSPOSED: Vt[(b*16+h)][hd][s], ld = 2048 (8B packed).
            const int h = ((n0 >> 6) & 15) + wc;
            const int sb2 = sbase + wr * 64;
#pragma unroll
            for (int i = 0; i < 4; ++i)
#pragma unroll
                for (int j = 0; j < 4; ++j) {
                    const int hd = j * 16 + l15;
                    const int s4 = sb2 + i * 16 + l4 * 4;
                    short4e p;
                    p[0] = (short)f2bf(acc[i][j][0]); p[1] = (short)f2bf(acc[i][j][1]);
                    p[2] = (short)f2bf(acc[i][j][2]); p[3] = (short)f2bf(acc[i][j][3]);
                    *(short4e*)(Vtws + ((size_t)(b * 16 + h) * 64 + hd) * 2048 + s4) = p;
                }
        } else {
            // Q/K: stage bf16 C-tile in LDS [128][136] (272B rows, 16B-aligned,
            // 4-bank row shift), then coalesced 16B stores.
            u16* Cl = &SB[0][0];
            const float qsc = which ? 1.0f : SC2;   // pre-scale Q for exp2-domain attn
#pragma unroll
            for (int i = 0; i < 4; ++i)
#pragma unroll
                for (int j = 0; j < 4; ++j)
#pragma unroll
                    for (int r = 0; r < 4; ++r)
                        Cl[(wr * 64 + i * 16 + l4 * 4 + r) * 136 +
                           wc * 64 + j * 16 + l15] = f2bf(acc[i][j][r] * qsc);
            __syncthreads();
            u16* dst = which ? Kws : Qws;
            const int hb = (n0 >> 6) & 15;
#pragma unroll
            for (int it = 0; it < 8; ++it) {
                const int c = tid + it * 256;        // 0..2047
                const int row = c >> 4, sub = c & 15;
                const int half = sub >> 3, off = (sub & 7) * 8;
                const short8 v = *(const short8*)(Cl + row * 136 + half * 64 + off);
                *(short8*)(dst + ((size_t)(b * 16 + hb + half) * 2048 + sbase + row) * 64
                               + off) = v;
            }
        }
    }
#undef GEMM_STAGE
}

// ---------------------------------------------------------------------------
// K-SPLIT MFMA flash attention (round-3 LDS body + flash-decode K split).
// Block = (bh, jt=q-block-of-128, seg of <=8 k-tiles64).  4 waves x 32 q.
// Per bh: jt 0..15, segs(jt)=ceil((jt+1)/4) -> 40 blocks; grid 1280.
// jt<4: single seg -> final write.  jt>=4: bf16 partial (O, m, l); combine
// kernel merges <=4 partials.  NOTE: plain launch_bounds(256) — a (256,4)
// minimum caps VGPR at 64 and spills ~150MB/dispatch to scratch (round 6).
// ---------------------------------------------------------------------------
__global__ __launch_bounds__(256) void attn_seg(
    const u16* __restrict__ Qg, const u16* __restrict__ Kg,
    const u16* __restrict__ Vtg, u16* __restrict__ Og,
    u16* __restrict__ Opart, float* __restrict__ Oml)
{
    __shared__ u16 KV[2][8192];    // per buffer: K[64][64] | V^T[64][64], XOR-swizzled

    static const int jt_of_u[40] = {0,1,2,3, 4,4, 5,5, 6,6, 7,7,
                                    8,8,8, 9,9,9, 10,10,10, 11,11,11,
                                    12,12,12,12, 13,13,13,13, 14,14,14,14, 15,15,15,15};
    static const int seg_of_u[40] = {0,0,0,0, 0,1, 0,1, 0,1, 0,1,
                                     0,1,2, 0,1,2, 0,1,2, 0,1,2,
                                     0,1,2,3, 0,1,2,3, 0,1,2,3, 0,1,2,3};

    const int tid = threadIdx.x;
    const int w = tid >> 6, lane = tid & 63;
    const int l31 = lane & 31, hi = lane >> 5;
    const int bid = blockIdx.x;
    const int u = 39 - (bid >> 5);          // heavy (jt=15) blocks dispatch first
    const int bh = bid & 31;                // bh%8 stable -> XCD-local KV reuse
    const int jt = jt_of_u[u], seg = seg_of_u[u];
    const int t0 = seg * 8;
    const int tmax = 2 * jt + 2;
    const int t1 = (tmax < t0 + 8) ? tmax : (t0 + 8);

    const u16* Qp = Qg + (size_t)bh * CS * CHD;
    const u16* Kp = Kg + (size_t)bh * CS * CHD;
    const u16* Vp = Vtg + (size_t)bh * CHD * CS;
    const int q0w = jt * 128 + w * 32;
    const int qrow = q0w + l31;

    // Q B-frags (pre-scaled by SC2): Q[qrow][c*16 + hi*8 + j]
    short8 qf[4];
#pragma unroll
    for (int c = 0; c < 4; ++c)
        qf[c] = *(const short8*)(Qp + (size_t)qrow * 64 + c * 16 + hi * 8);

    f32x16 o0, o1;
#pragma unroll
    for (int r = 0; r < 16; ++r) { o0[r] = 0.f; o1[r] = 0.f; }
    float m_run = -1e30f, l_run = 0.f;

    short8 stg[4];
#define ATTN_ISSUE(K0)                                                           \
    {                                                                            \
        _Pragma("unroll")                                                        \
        for (int it = 0; it < 4; ++it) {                                         \
            const int c = tid + it * 256;                                        \
            const int ob = c * 16;                                               \
            const u16* src;                                                      \
            if (ob < 8192) { const int row = ob >> 7, cs = (ob >> 4) & 7;        \
                src = Kp + (size_t)((K0) + row) * 64 + cs * 8; }                 \
            else { const int o2 = ob - 8192; const int row = o2 >> 7,            \
                cs = (o2 >> 4) & 7;                                              \
                src = Vp + (size_t)row * CS + (K0) + cs * 8; }                   \
            stg[it] = *(const short8*)src;                                       \
        }                                                                        \
    }
#define ATTN_WRITE(BUF)                                                          \
    {                                                                            \
        _Pragma("unroll")                                                        \
        for (int it = 0; it < 4; ++it) {                                         \
            const int c = tid + it * 256;                                        \
            const int ob = c * 16;                                               \
            int db;                                                              \
            if (ob < 8192) { const int row = ob >> 7; db = ob ^ ((row & 7) << 4); } \
            else { const int o2 = ob - 8192; const int row = o2 >> 7;            \
                db = 8192 + (o2 ^ ((row & 7) << 4)); }                           \
            *(short8*)((char*)&KV[BUF][0] + db) = stg[it];                       \
        }                                                                        \
    }

    ATTN_ISSUE(t0 * 64);
    ATTN_WRITE(0);
    __syncthreads();

    for (int kt = t0; kt < t1; ++kt) {
        const int k0 = kt * 64;
        const int cur = (kt - t0) & 1;
        if (kt + 1 < t1) ATTN_ISSUE((kt + 1) * 64);

        if (k0 <= q0w + 31) {
            const char* Kl = (const char*)&KV[cur][0];
            const char* Vl = (const char*)&KV[cur][4096];
            const bool edge = (k0 + 63 > q0w);
            const bool do_hi = (k0 + 32 <= q0w + 31);

            // ---- S^T = K * Q^T : lane owns q-col = l31 (verified 32x32 C layout)
            f32x16 s0, s1;
#pragma unroll
            for (int r = 0; r < 16; ++r) s0[r] = 0.f;
            __builtin_amdgcn_s_setprio(1);
#pragma unroll
            for (int c = 0; c < 4; ++c) {
                const int row = l31;
                const short8 kf = *(const short8*)(Kl + row * 128 +
                                    ((c * 32 + hi * 16) ^ ((row & 7) << 4)));
                s0 = __builtin_amdgcn_mfma_f32_32x32x16_bf16(kf, qf[c], s0, 0, 0, 0);
            }
            if (do_hi) {
#pragma unroll
                for (int r = 0; r < 16; ++r) s1[r] = 0.f;
#pragma unroll
                for (int c = 0; c < 4; ++c) {
                    const int row = 32 + l31;
                    const short8 kf = *(const short8*)(Kl + row * 128 +
                                        ((c * 32 + hi * 16) ^ ((row & 7) << 4)));
                    s1 = __builtin_amdgcn_mfma_f32_32x32x16_bf16(kf, qf[c], s1, 0, 0, 0);
                }
            }
            __builtin_amdgcn_s_setprio(0);

            // ---- causal mask + row max (scores already exp2-domain scaled)
            float pmax = -1e30f;
#pragma unroll
            for (int r = 0; r < 16; ++r) {
                float a0 = s0[r];
                if (edge) {
                    const int koff = (r & 3) + 8 * (r >> 2) + 4 * hi;   // crow(r,hi)
                    if (k0 + koff > qrow) a0 = -1e30f;
                }
                s0[r] = a0;
                pmax = fmaxf(pmax, a0);
            }
            if (do_hi) {
#pragma unroll
                for (int r = 0; r < 16; ++r) {
                    float a1 = s1[r];
                    if (edge) {
                        const int koff = (r & 3) + 8 * (r >> 2) + 4 * hi;
                        if (k0 + 32 + koff > qrow) a1 = -1e30f;
                    }
                    s1[r] = a1;
                    pmax = fmaxf(pmax, a1);
                }
            }
            pmax = fmaxf(pmax, __shfl_xor(pmax, 32));

            // ---- defer-max rescale (rare)
            if (!__all(pmax - m_run <= DEFER_THR)) {
                const float mn = fmaxf(m_run, pmax);
                const float al = EXP2F(m_run - mn);
                l_run *= al;
                m_run = mn;
#pragma unroll
                for (int r = 0; r < 16; ++r) {
                    const int qq = (r & 3) + 8 * (r >> 2) + 4 * hi;
                    const float av = __shfl(al, qq);
                    o0[r] *= av; o1[r] *= av;
                }
            }

            // ---- P = exp2(s - m), row-sum
            float lsum = 0.f;
#pragma unroll
            for (int r = 0; r < 16; ++r) {
                const float p0 = EXP2F(s0[r] - m_run);
                s0[r] = p0; lsum += p0;
            }
            if (do_hi) {
#pragma unroll
                for (int r = 0; r < 16; ++r) {
                    const float p1 = EXP2F(s1[r] - m_run);
                    s1[r] = p1; lsum += p1;
                }
            }
            lsum += __shfl_xor(lsum, 32);
            l_run += lsum;

            // ---- P -> A-frags in-register (T12) + PV from swizzled LDS V^T
#define PV_STEP(KS, SV)                                                          \
            {                                                                    \
                const int rb = ((KS) & 1) * 8;                                   \
                u32 w0 = pkbf(SV[rb + 0], SV[rb + 1]);                           \
                u32 w1 = pkbf(SV[rb + 2], SV[rb + 3]);                           \
                u32 w2 = pkbf(SV[rb + 4], SV[rb + 5]);                           \
                u32 w3 = pkbf(SV[rb + 6], SV[rb + 7]);                           \
                asm("v_permlane32_swap_b32 %0, %1" : "+v"(w0), "+v"(w2));        \
                asm("v_permlane32_swap_b32 %0, %1" : "+v"(w1), "+v"(w3));        \
                union { u32 uw[4]; short8 v; } pu;                               \
                pu.uw[0] = w0; pu.uw[1] = w1; pu.uw[2] = w2; pu.uw[3] = w3;      \
                const short8 pa = pu.v;                                          \
                const int vr0 = l31, vr1 = 32 + l31;                             \
                const short8 v0 = *(const short8*)(Vl + vr0 * 128 +              \
                                    (((KS) * 32 + hi * 16) ^ ((vr0 & 7) << 4))); \
                const short8 v1 = *(const short8*)(Vl + vr1 * 128 +              \
                                    (((KS) * 32 + hi * 16) ^ ((vr1 & 7) << 4))); \
                __builtin_amdgcn_s_setprio(1);                                   \
                o0 = __builtin_amdgcn_mfma_f32_32x32x16_bf16(pa, v0, o0, 0, 0, 0);\
                o1 = __builtin_amdgcn_mfma_f32_32x32x16_bf16(pa, v1, o1, 0, 0, 0);\
                __builtin_amdgcn_s_setprio(0);                                   \
            }
            PV_STEP(0, s0)
            PV_STEP(1, s0)
            if (do_hi) {
                PV_STEP(2, s1)
                PV_STEP(3, s1)
            }
#undef PV_STEP
        }

        if (kt + 1 < t1) ATTN_WRITE(cur ^ 1);
        __syncthreads();
    }

    if (jt < 4) {
        // single segment: normalize + final store to [B][S][D]
        const float invl = 1.f / l_run;
#pragma unroll
        for (int g = 0; g < 4; ++g)
#pragma unroll
            for (int c = 0; c < 4; ++c) {
                const int qq = 8 * g + 4 * hi + c;       // crow(4g+c, hi)
                const float av = __shfl(invl, qq);
                u16* dst = Og + ((size_t)(bh >> 4) * CS + jt * 128 + w * 32 + qq) * CD
                             + (bh & 15) * 64 + l31;
                dst[0]  = f2bf(o0[g * 4 + c] * av);
                dst[32] = f2bf(o1[g * 4 + c] * av);
            }
    } else {
        // partial store: slot = bh*36 + (u-4); rows w*32..+31, unnormalized
        const int slot = bh * 36 + (u - 4);
        u16* pd = Opart + ((size_t)slot * 128 + w * 32) * 64;
#pragma unroll
        for (int g = 0; g < 4; ++g)
#pragma unroll
            for (int c = 0; c < 4; ++c) {
                const int qq = 8 * g + 4 * hi + c;
                pd[qq * 64 + l31]      = f2bf(o0[g * 4 + c]);
                pd[qq * 64 + 32 + l31] = f2bf(o1[g * 4 + c]);
            }
        if (lane < 32) {
            const size_t mi = ((size_t)slot * 128 + w * 32 + l31) * 2;
            Oml[mi]     = m_run;
            Oml[mi + 1] = l_run;
        }
    }
#undef ATTN_ISSUE
#undef ATTN_WRITE
}

// ---------------------------------------------------------------------------
// Combine <=4 K-split partials per q-row (jt>=4 only).  Memory-bound.
// Block = (jt-4, bh); thread t: row = t>>1, cols = (t&1)*32..+31.
// ---------------------------------------------------------------------------
__global__ __launch_bounds__(256) void attn_combine(
    const u16* __restrict__ Opart, const float* __restrict__ Oml,
    u16* __restrict__ Og)
{
    static const int ub[16] = {0,1,2,3,4,6,8,10,12,15,18,21,24,28,32,36};
    const int jt = 4 + blockIdx.x;
    const int bh = blockIdx.y;
    const int tid = threadIdx.x;
    const int r = tid >> 1, half = tid & 1;
    const int segs = (jt + 4) >> 2;          // ceil((jt+1)/4)
    const int slot0 = bh * 36 + ub[jt] - 4;

    float acc[32];
#pragma unroll
    for (int k = 0; k < 32; ++k) acc[k] = 0.f;
    float M = -1e30f, L = 0.f;

    for (int i = 0; i < segs; ++i) {
        const int slot = slot0 + i;
        const float mi = Oml[((size_t)slot * 128 + r) * 2];
        const float li = Oml[((size_t)slot * 128 + r) * 2 + 1];
        float wi;
        if (mi > M) {
            const float sc = EXP2F(M - mi);
#pragma unroll
            for (int k = 0; k < 32; ++k) acc[k] *= sc;
            L *= sc; M = mi; wi = 1.f;
        } else {
            wi = EXP2F(mi - M);
        }
        const u16* op = Opart + ((size_t)slot * 128 + r) * 64 + half * 32;
#pragma unroll
        for (int v = 0; v < 4; ++v) {
            const short8 x = *(const short8*)(op + v * 8);
#pragma unroll
            for (int e = 0; e < 8; ++e)
                acc[v * 8 + e] += wi * bf2f(x[e]);
        }
        L += wi * li;
    }

    const float inv = 1.f / L;
    const int b = bh >> 4, h = bh & 15;
    const int q = jt * 128 + r;
    u16* dst = Og + ((size_t)(b * CS + q)) * CD + h * 64 + half * 32;
#pragma unroll
    for (int v = 0; v < 4; ++v) {
        short8 y;
#pragma unroll
        for (int e = 0; e < 8; ++e) y[e] = (short)f2bf(acc[v * 8 + e] * inv);
        *(short8*)(dst + v * 8) = y;
    }
}

// ---------------------------------------------------------------------------
extern "C" void kernel_launch(void* const* d_in, const int* in_sizes, int n_in,
                              void* d_out, int out_size, void* d_ws, size_t ws_size,
                              hipStream_t stream)
{
    const float* x     = (const float*)d_in[0];   // (B,S,D)
    const float* w_qkv = (const float*)d_in[1];   // (D,3D)
    const float* w_out = (const float*)d_in[2];   // (D,D)
    float* out = (float*)d_out;                   // (B,S,D) f32

    u16* xb    = (u16*)d_ws;                      // [4096][1024]
    u16* wqkvT = xb    + (size_t)4096 * 1024;     // [3072][1024]
    u16* woutT = wqkvT + (size_t)3072 * 1024;     // [1024][1024]
    u16* Qws   = woutT + (size_t)1024 * 1024;     // [32][2048][64]  (SC2-scaled)
    u16* Kws   = Qws   + (size_t)32 * 2048 * 64;
    u16* Vtws  = Kws   + (size_t)32 * 2048 * 64;  // [32][64][2048]
    u16* Ob    = Vtws  + (size_t)32 * 2048 * 64;  // [4096][1024] bf16
    u16* Opart = Ob    + (size_t)4096 * 1024;     // [1152][128][64] bf16 partials
    float* Oml = (float*)(Opart + (size_t)1152 * 128 * 64);  // [1152][128][2] f32

    cvt_x<<<2048, 256, 0, stream>>>(x, xb);
    txw<<<dim3(48, 16), 256, 0, stream>>>(w_qkv, wqkvT, 3072);
    txw<<<dim3(16, 16), 256, 0, stream>>>(w_out, woutT, 1024);

    gemm_mfma<<<dim3(24, 32), 256, 0, stream>>>(xb, wqkvT, 0, Qws, Kws, Vtws, nullptr);
    attn_seg<<<1280, 256, 0, stream>>>(Qws, Kws, Vtws, Ob, Opart, Oml);
    attn_combine<<<dim3(12, 32), 256, 0, stream>>>(Opart, Oml, Ob);
    gemm_mfma<<<dim3(8, 32), 256, 0, stream>>>(Ob, woutT, 1, nullptr, nullptr, nullptr, out);
}

// Round 9
// 197.718 us; speedup vs baseline: 1.1784x; 1.0203x over previous
//
#include <hip/hip_runtime.h>
#include <hip/hip_bf16.h>
#include <stdint.h>

typedef unsigned short u16;
typedef unsigned int u32;
typedef __attribute__((ext_vector_type(8))) short short8;    // 8 bf16 = 4 VGPR (MFMA A/B frag)
typedef __attribute__((ext_vector_type(4))) short short4e;   // 8B packed store
typedef __attribute__((ext_vector_type(4))) float f32x4;     // 16x16 MFMA C/D frag
typedef __attribute__((ext_vector_type(16))) float f32x16;   // 32x32 MFMA C/D frag

constexpr int CB = 2, CS = 2048, CD = 1024, CH = 16, CHD = 64;
constexpr float SC2 = 0.125f * 1.44269504088896f;   // scale * log2(e): exp2 domain
constexpr float DEFER_THR = 11.0f;                  // P bounded by 2^11

__device__ __forceinline__ u16 f2bf(float f) {
    unsigned u = __float_as_uint(f);
    u += 0x7fffu + ((u >> 16) & 1u);     // RNE
    return (u16)(u >> 16);
}
__device__ __forceinline__ float bf2f(short s) {
    return __uint_as_float(((u32)(unsigned short)s) << 16);
}

#if __has_builtin(__builtin_amdgcn_exp2f)
#define EXP2F(x) __builtin_amdgcn_exp2f(x)
#else
#define EXP2F(x) exp2f(x)
#endif

// pack two f32 -> u32 of 2 bf16 (lo = a, hi = b)
__device__ __forceinline__ u32 pkbf(float a, float b) {
    u32 r;
    asm("v_cvt_pk_bf16_f32 %0, %1, %2" : "=v"(r) : "v"(a), "v"(b));
    return r;
}

// ---------------------------------------------------------------------------
// Fused prep: bid<2048: x f32->bf16 (8/thread).  2048..2815: w_qkv transpose.
// >=2816: w_out transpose.  (one launch instead of three)
// ---------------------------------------------------------------------------
__global__ __launch_bounds__(256) void prep(
    const float* __restrict__ X, u16* __restrict__ Y,
    const float* __restrict__ Wq, u16* __restrict__ WqT,
    const float* __restrict__ Wo, u16* __restrict__ WoT)
{
    __shared__ u16 T[64][80];
    const int bid = blockIdx.x;
    const int t = threadIdx.x;
    if (bid < 2048) {
        const int i = (bid * 256 + t) * 8;
        const float4 v0 = *(const float4*)(X + i);
        const float4 v1 = *(const float4*)(X + i + 4);
        short8 r;
        r[0] = (short)f2bf(v0.x); r[1] = (short)f2bf(v0.y);
        r[2] = (short)f2bf(v0.z); r[3] = (short)f2bf(v0.w);
        r[4] = (short)f2bf(v1.x); r[5] = (short)f2bf(v1.y);
        r[6] = (short)f2bf(v1.z); r[7] = (short)f2bf(v1.w);
        *(short8*)(Y + i) = r;
        return;
    }
    const bool qkv = (bid < 2816);
    const int idx = qkv ? (bid - 2048) : (bid - 2816);
    const int nb = qkv ? 48 : 16;
    const int ldw = qkv ? 3072 : 1024;
    const float* W = qkv ? Wq : Wo;
    u16* Bt = qkv ? WqT : WoT;
    const int n0 = (idx % nb) * 64, k0 = (idx / nb) * 64;
    const int r = t >> 4, c4 = (t & 15) * 4;
#pragma unroll
    for (int p = 0; p < 4; ++p) {
        const int kr = r + p * 16;
        const float4 v = *(const float4*)(W + (size_t)(k0 + kr) * ldw + n0 + c4);
        T[c4 + 0][kr] = f2bf(v.x); T[c4 + 1][kr] = f2bf(v.y);
        T[c4 + 2][kr] = f2bf(v.z); T[c4 + 3][kr] = f2bf(v.w);
    }
    __syncthreads();
    const int rr = t >> 2, cc = (t & 3) * 16;
    const short8 a = *(const short8*)((const char*)&T[0][0] + rr * 160 + cc * 2);
    const short8 b = *(const short8*)((const char*)&T[0][0] + rr * 160 + cc * 2 + 16);
    u16* dst = Bt + (size_t)(n0 + rr) * 1024 + k0 + cc;
    *(short8*)dst = a;
    *(short8*)(dst + 8) = b;
}

// ---------------------------------------------------------------------------
// bf16 MFMA GEMM, 128xBN tile, BK=32, 4 waves (2x2), double-buffered LDS,
// async global_load_lds (width 16) staging, 1 barrier per K-step.  K = 1024.
// BN=128 mode 0: scatter QKV per head (Q pre-scaled by SC2), LDS epilogue.
// BN=64/128 mode 1: f32 direct write (BN=64 -> 512 blocks for out-proj).
// ---------------------------------------------------------------------------
template<int BN>
__global__ __launch_bounds__(256) void gemm_mfma(
    const u16* __restrict__ A, const u16* __restrict__ Bt, int mode,
    u16* __restrict__ Qws, u16* __restrict__ Kws, u16* __restrict__ Vtws,
    float* __restrict__ Cf)
{
    constexpr int NJ = BN / 32;                  // per-wave 16-col frags
    constexpr int NCHUNK = (128 + BN) * 32 / 8;  // 16B chunks per buffer
    constexpr int LDSE = (BN == 128) ? 8704 : (128 + BN) * 32;
    __shared__ u16 SB[2][LDSE];
    const int tid = threadIdx.x;
    const int w = tid >> 6, lane = tid & 63;
    const int l15 = lane & 15, l4 = lane >> 4;
    const int wr = w >> 1, wc = w & 1;
    const int n0 = blockIdx.x * BN, m0 = blockIdx.y * 128;

    f32x4 acc[4][NJ];
    const f32x4 zf = {0.f, 0.f, 0.f, 0.f};
#pragma unroll
    for (int i = 0; i < 4; ++i)
#pragma unroll
        for (int j = 0; j < NJ; ++j) acc[i][j] = zf;

#define GEMM_STAGE(BUF, K0)                                                     \
    {                                                                           \
        _Pragma("unroll")                                                       \
        for (int it = 0; it < NCHUNK / 256; ++it) {                             \
            const int c = tid + it * 256;                                       \
            const u16* src;                                                     \
            if (c < 512) { const int row = c >> 2, cs = c & 3;                  \
                src = A + (size_t)(m0 + row) * 1024 + (K0) + cs * 8; }          \
            else { const int c2 = c - 512; const int row = c2 >> 2, cs = c2 & 3;\
                src = Bt + (size_t)(n0 + row) * 1024 + (K0) + cs * 8; }         \
            __builtin_amdgcn_global_load_lds(                                   \
                (const __attribute__((address_space(1))) unsigned int*)src,     \
                (__attribute__((address_space(3))) unsigned int*)&SB[BUF][c*8], \
                16, 0, 0);                                                      \
        }                                                                       \
    }

    GEMM_STAGE(0, 0);
    __syncthreads();

    for (int t = 0; t < 32; ++t) {
        const int cur = t & 1;
        if (t < 31) GEMM_STAGE(cur ^ 1, (t + 1) * 32);

        const u16* Al = &SB[cur][0];
        const u16* Bl = &SB[cur][4096];
        short8 a[4], b[NJ];
#pragma unroll
        for (int i = 0; i < 4; ++i)
            a[i] = *(const short8*)(Al + (wr * 64 + i * 16 + l15) * 32 + l4 * 8);
#pragma unroll
        for (int j = 0; j < NJ; ++j)
            b[j] = *(const short8*)(Bl + (wc * (BN / 2) + j * 16 + l15) * 32 + l4 * 8);
        __builtin_amdgcn_s_setprio(1);
#pragma unroll
        for (int i = 0; i < 4; ++i)
#pragma unroll
            for (int j = 0; j < NJ; ++j)
                acc[i][j] = __builtin_amdgcn_mfma_f32_16x16x32_bf16(a[i], b[j], acc[i][j], 0, 0, 0);
        __builtin_amdgcn_s_setprio(0);
        __syncthreads();
    }

    // C/D layout (16x16): col = lane&15, row = (lane>>4)*4 + reg.
    if (mode == 1) {
#pragma unroll
        for (int i = 0; i < 4; ++i)
#pragma unroll
            for (int j = 0; j < NJ; ++j)
#pragma unroll
                for (int r = 0; r < 4; ++r)
                    Cf[(size_t)(m0 + wr * 64 + i * 16 + l4 * 4 + r) * 1024 +
                       n0 + wc * (BN / 2) + j * 16 + l15] = acc[i][j][r];
    } else if constexpr (BN == 128) {
        // which is block-uniform (n0 is a multiple of 128).
        const int which = n0 >> 10;           // 0=q 1=k 2=v
        const int b = m0 >> 11;
        const int sbase = m0 & 2047;
        if (which == 2) {
            // V stored TRANSPOSED: Vt[(b*16+h)][hd][s], ld = 2048 (8B packed).
            const int h = ((n0 >> 6) & 15) + wc;
            const int sb2 = sbase + wr * 64;
#pragma unroll
            for (int i = 0; i < 4; ++i)
#pragma unroll
                for (int j = 0; j < 4; ++j) {
                    const int hd = j * 16 + l15;
                    const int s4 = sb2 + i * 16 + l4 * 4;
                    short4e p;
                    p[0] = (short)f2bf(acc[i][j][0]); p[1] = (short)f2bf(acc[i][j][1]);
                    p[2] = (short)f2bf(acc[i][j][2]); p[3] = (short)f2bf(acc[i][j][3]);
                    *(short4e*)(Vtws + ((size_t)(b * 16 + h) * 64 + hd) * 2048 + s4) = p;
                }
        } else {
            // Q/K: stage bf16 C-tile in LDS [128][136], then coalesced stores.
            u16* Cl = &SB[0][0];
            const float qsc = which ? 1.0f : SC2;   // pre-scale Q for exp2-domain attn
#pragma unroll
            for (int i = 0; i < 4; ++i)
#pragma unroll
                for (int j = 0; j < 4; ++j)
#pragma unroll
                    for (int r = 0; r < 4; ++r)
                        Cl[(wr * 64 + i * 16 + l4 * 4 + r) * 136 +
                           wc * 64 + j * 16 + l15] = f2bf(acc[i][j][r] * qsc);
            __syncthreads();
            u16* dst = which ? Kws : Qws;
            const int hb = (n0 >> 6) & 15;
#pragma unroll
            for (int it = 0; it < 8; ++it) {
                const int c = tid + it * 256;        // 0..2047
                const int row = c >> 4, sub = c & 15;
                const int half = sub >> 3, off = (sub & 7) * 8;
                const short8 v = *(const short8*)(Cl + row * 136 + half * 64 + off);
                *(short8*)(dst + ((size_t)(b * 16 + hb + half) * 2048 + sbase + row) * 64
                               + off) = v;
            }
        }
    }
#undef GEMM_STAGE
}

// ---------------------------------------------------------------------------
// K-SPLIT MFMA flash attention.  Block = (bh, jt, seg of <=8 k-tiles64),
// 4 waves x 32 q.  Staging via global_load_lds with PRE-SWIZZLED SOURCE
// (rule #21: linear LDS dest, source chunk j^(row&7) within each 128B row;
// reads keep the matching XOR) — no stg regs, no ds_writes.
// jt<4: final write.  jt>=4: bf16 partial (O,m,l) -> combine kernel.
// NOTE: plain launch_bounds(256) — (256,4) caps VGPR at 64 and spills (r6).
// ---------------------------------------------------------------------------
__global__ __launch_bounds__(256) void attn_seg(
    const u16* __restrict__ Qg, const u16* __restrict__ Kg,
    const u16* __restrict__ Vtg, u16* __restrict__ Og,
    u16* __restrict__ Opart, float* __restrict__ Oml)
{
    __shared__ u16 KV[2][8192];    // per buffer: K[64][64] | V^T[64][64], XOR-swizzled

    static const int jt_of_u[40] = {0,1,2,3, 4,4, 5,5, 6,6, 7,7,
                                    8,8,8, 9,9,9, 10,10,10, 11,11,11,
                                    12,12,12,12, 13,13,13,13, 14,14,14,14, 15,15,15,15};
    static const int seg_of_u[40] = {0,0,0,0, 0,1, 0,1, 0,1, 0,1,
                                     0,1,2, 0,1,2, 0,1,2, 0,1,2,
                                     0,1,2,3, 0,1,2,3, 0,1,2,3, 0,1,2,3};

    const int tid = threadIdx.x;
    const int w = tid >> 6, lane = tid & 63;
    const int l31 = lane & 31, hi = lane >> 5;
    const int bid = blockIdx.x;
    const int u = 39 - (bid >> 5);          // heavy (jt=15) blocks dispatch first
    const int bh = bid & 31;                // bh%8 stable -> XCD-local KV reuse
    const int jt = jt_of_u[u], seg = seg_of_u[u];
    const int t0 = seg * 8;
    const int tmax = 2 * jt + 2;
    const int t1 = (tmax < t0 + 8) ? tmax : (t0 + 8);

    const u16* Qp = Qg + (size_t)bh * CS * CHD;
    const u16* Kp = Kg + (size_t)bh * CS * CHD;
    const u16* Vp = Vtg + (size_t)bh * CHD * CS;
    const int q0w = jt * 128 + w * 32;
    const int qrow = q0w + l31;

    // Q B-frags (pre-scaled by SC2): Q[qrow][c*16 + hi*8 + j]
    short8 qf[4];
#pragma unroll
    for (int c = 0; c < 4; ++c)
        qf[c] = *(const short8*)(Qp + (size_t)qrow * 64 + c * 16 + hi * 8);

    f32x16 o0, o1;
#pragma unroll
    for (int r = 0; r < 16; ++r) { o0[r] = 0.f; o1[r] = 0.f; }
    float m_run = -1e30f, l_run = 0.f;

    // async stage: LDS dest LINEAR (c*16); source 16B-chunk index XORed with
    // (row&7) inside the row -> LDS content identical to old swizzled writes.
#define ATTN_GSTAGE(BUF, K0)                                                     \
    {                                                                            \
        _Pragma("unroll")                                                        \
        for (int it = 0; it < 4; ++it) {                                         \
            const int c = tid + it * 256;                                        \
            const int ob = c * 16;                                               \
            const u16* src;                                                      \
            if (ob < 8192) { const int row = ob >> 7, j = (ob >> 4) & 7;         \
                src = Kp + (size_t)((K0) + row) * 64 + 8 * (j ^ (row & 7)); }    \
            else { const int o2 = ob - 8192; const int row = o2 >> 7,            \
                j = (o2 >> 4) & 7;                                               \
                src = Vp + (size_t)row * CS + (K0) + 8 * (j ^ (row & 7)); }      \
            __builtin_amdgcn_global_load_lds(                                    \
                (const __attribute__((address_space(1))) unsigned int*)src,      \
                (__attribute__((address_space(3))) unsigned int*)&KV[BUF][c*8],  \
                16, 0, 0);                                                       \
        }                                                                        \
    }

    ATTN_GSTAGE(0, t0 * 64);
    __syncthreads();

    for (int kt = t0; kt < t1; ++kt) {
        const int k0 = kt * 64;
        const int cur = (kt - t0) & 1;
        if (kt + 1 < t1) ATTN_GSTAGE(cur ^ 1, (kt + 1) * 64);

        if (k0 <= q0w + 31) {
            const char* Kl = (const char*)&KV[cur][0];
            const char* Vl = (const char*)&KV[cur][4096];
            const bool edge = (k0 + 63 > q0w);
            const bool do_hi = (k0 + 32 <= q0w + 31);

            // ---- S^T = K * Q^T : lane owns q-col = l31 (verified 32x32 C layout)
            f32x16 s0, s1;
#pragma unroll
            for (int r = 0; r < 16; ++r) s0[r] = 0.f;
            __builtin_amdgcn_s_setprio(1);
#pragma unroll
            for (int c = 0; c < 4; ++c) {
                const int row = l31;
                const short8 kf = *(const short8*)(Kl + row * 128 +
                                    ((c * 32 + hi * 16) ^ ((row & 7) << 4)));
                s0 = __builtin_amdgcn_mfma_f32_32x32x16_bf16(kf, qf[c], s0, 0, 0, 0);
            }
            if (do_hi) {
#pragma unroll
                for (int r = 0; r < 16; ++r) s1[r] = 0.f;
#pragma unroll
                for (int c = 0; c < 4; ++c) {
                    const int row = 32 + l31;
                    const short8 kf = *(const short8*)(Kl + row * 128 +
                                        ((c * 32 + hi * 16) ^ ((row & 7) << 4)));
                    s1 = __builtin_amdgcn_mfma_f32_32x32x16_bf16(kf, qf[c], s1, 0, 0, 0);
                }
            }
            __builtin_amdgcn_s_setprio(0);

            // ---- causal mask + row max (scores already exp2-domain scaled)
            float pmax = -1e30f;
#pragma unroll
            for (int r = 0; r < 16; ++r) {
                float a0 = s0[r];
                if (edge) {
                    const int koff = (r & 3) + 8 * (r >> 2) + 4 * hi;   // crow(r,hi)
                    if (k0 + koff > qrow) a0 = -1e30f;
                }
                s0[r] = a0;
                pmax = fmaxf(pmax, a0);
            }
            if (do_hi) {
#pragma unroll
                for (int r = 0; r < 16; ++r) {
                    float a1 = s1[r];
                    if (edge) {
                        const int koff = (r & 3) + 8 * (r >> 2) + 4 * hi;
                        if (k0 + 32 + koff > qrow) a1 = -1e30f;
                    }
                    s1[r] = a1;
                    pmax = fmaxf(pmax, a1);
                }
            }
            pmax = fmaxf(pmax, __shfl_xor(pmax, 32));

            // ---- defer-max rescale (rare)
            if (!__all(pmax - m_run <= DEFER_THR)) {
                const float mn = fmaxf(m_run, pmax);
                const float al = EXP2F(m_run - mn);
                l_run *= al;
                m_run = mn;
#pragma unroll
                for (int r = 0; r < 16; ++r) {
                    const int qq = (r & 3) + 8 * (r >> 2) + 4 * hi;
                    const float av = __shfl(al, qq);
                    o0[r] *= av; o1[r] *= av;
                }
            }

            // ---- P = exp2(s - m), row-sum
            float lsum = 0.f;
#pragma unroll
            for (int r = 0; r < 16; ++r) {
                const float p0 = EXP2F(s0[r] - m_run);
                s0[r] = p0; lsum += p0;
            }
            if (do_hi) {
#pragma unroll
                for (int r = 0; r < 16; ++r) {
                    const float p1 = EXP2F(s1[r] - m_run);
                    s1[r] = p1; lsum += p1;
                }
            }
            lsum += __shfl_xor(lsum, 32);
            l_run += lsum;

            // ---- P -> A-frags in-register (T12) + PV from swizzled LDS V^T
#define PV_STEP(KS, SV)                                                          \
            {                                                                    \
                const int rb = ((KS) & 1) * 8;                                   \
                u32 w0 = pkbf(SV[rb + 0], SV[rb + 1]);                           \
                u32 w1 = pkbf(SV[rb + 2], SV[rb + 3]);                           \
                u32 w2 = pkbf(SV[rb + 4], SV[rb + 5]);                           \
                u32 w3 = pkbf(SV[rb + 6], SV[rb + 7]);                           \
                asm("v_permlane32_swap_b32 %0, %1" : "+v"(w0), "+v"(w2));        \
                asm("v_permlane32_swap_b32 %0, %1" : "+v"(w1), "+v"(w3));        \
                union { u32 uw[4]; short8 v; } pu;                               \
                pu.uw[0] = w0; pu.uw[1] = w1; pu.uw[2] = w2; pu.uw[3] = w3;      \
                const short8 pa = pu.v;                                          \
                const int vr0 = l31, vr1 = 32 + l31;                             \
                const short8 v0 = *(const short8*)(Vl + vr0 * 128 +              \
                                    (((KS) * 32 + hi * 16) ^ ((vr0 & 7) << 4))); \
                const short8 v1 = *(const short8*)(Vl + vr1 * 128 +              \
                                    (((KS) * 32 + hi * 16) ^ ((vr1 & 7) << 4))); \
                __builtin_amdgcn_s_setprio(1);                                   \
                o0 = __builtin_amdgcn_mfma_f32_32x32x16_bf16(pa, v0, o0, 0, 0, 0);\
                o1 = __builtin_amdgcn_mfma_f32_32x32x16_bf16(pa, v1, o1, 0, 0, 0);\
                __builtin_amdgcn_s_setprio(0);                                   \
            }
            PV_STEP(0, s0)
            PV_STEP(1, s0)
            if (do_hi) {
                PV_STEP(2, s1)
                PV_STEP(3, s1)
            }
#undef PV_STEP
        }

        __syncthreads();   // drains in-flight global_load_lds (vmcnt) + joins waves
    }

    if (jt < 4) {
        // single segment: normalize + final store to [B][S][D]
        const float invl = 1.f / l_run;
#pragma unroll
        for (int g = 0; g < 4; ++g)
#pragma unroll
            for (int c = 0; c < 4; ++c) {
                const int qq = 8 * g + 4 * hi + c;       // crow(4g+c, hi)
                const float av = __shfl(invl, qq);
                u16* dst = Og + ((size_t)(bh >> 4) * CS + jt * 128 + w * 32 + qq) * CD
                             + (bh & 15) * 64 + l31;
                dst[0]  = f2bf(o0[g * 4 + c] * av);
                dst[32] = f2bf(o1[g * 4 + c] * av);
            }
    } else {
        // partial store: slot = bh*36 + (u-4); rows w*32..+31, unnormalized
        const int slot = bh * 36 + (u - 4);
        u16* pd = Opart + ((size_t)slot * 128 + w * 32) * 64;
#pragma unroll
        for (int g = 0; g < 4; ++g)
#pragma unroll
            for (int c = 0; c < 4; ++c) {
                const int qq = 8 * g + 4 * hi + c;
                pd[qq * 64 + l31]      = f2bf(o0[g * 4 + c]);
                pd[qq * 64 + 32 + l31] = f2bf(o1[g * 4 + c]);
            }
        if (lane < 32) {
            const size_t mi = ((size_t)slot * 128 + w * 32 + l31) * 2;
            Oml[mi]     = m_run;
            Oml[mi + 1] = l_run;
        }
    }
#undef ATTN_GSTAGE
}

// ---------------------------------------------------------------------------
// Combine <=4 K-split partials per q-row (jt>=4 only).  Memory-bound.
// ---------------------------------------------------------------------------
__global__ __launch_bounds__(256) void attn_combine(
    const u16* __restrict__ Opart, const float* __restrict__ Oml,
    u16* __restrict__ Og)
{
    static const int ub[16] = {0,1,2,3,4,6,8,10,12,15,18,21,24,28,32,36};
    const int jt = 4 + blockIdx.x;
    const int bh = blockIdx.y;
    const int tid = threadIdx.x;
    const int r = tid >> 1, half = tid & 1;
    const int segs = (jt + 4) >> 2;          // ceil((jt+1)/4)
    const int slot0 = bh * 36 + ub[jt] - 4;

    float acc[32];
#pragma unroll
    for (int k = 0; k < 32; ++k) acc[k] = 0.f;
    float M = -1e30f, L = 0.f;

    for (int i = 0; i < segs; ++i) {
        const int slot = slot0 + i;
        const float mi = Oml[((size_t)slot * 128 + r) * 2];
        const float li = Oml[((size_t)slot * 128 + r) * 2 + 1];
        float wi;
        if (mi > M) {
            const float sc = EXP2F(M - mi);
#pragma unroll
            for (int k = 0; k < 32; ++k) acc[k] *= sc;
            L *= sc; M = mi; wi = 1.f;
        } else {
            wi = EXP2F(mi - M);
        }
        const u16* op = Opart + ((size_t)slot * 128 + r) * 64 + half * 32;
#pragma unroll
        for (int v = 0; v < 4; ++v) {
            const short8 x = *(const short8*)(op + v * 8);
#pragma unroll
            for (int e = 0; e < 8; ++e)
                acc[v * 8 + e] += wi * bf2f(x[e]);
        }
        L += wi * li;
    }

    const float inv = 1.f / L;
    const int q = jt * 128 + r;
    u16* dst = Og + ((size_t)((bh >> 4) * CS + q)) * CD + (bh & 15) * 64 + half * 32;
#pragma unroll
    for (int v = 0; v < 4; ++v) {
        short8 y;
#pragma unroll
        for (int e = 0; e < 8; ++e) y[e] = (short)f2bf(acc[v * 8 + e] * inv);
        *(short8*)(dst + v * 8) = y;
    }
}

// ---------------------------------------------------------------------------
extern "C" void kernel_launch(void* const* d_in, const int* in_sizes, int n_in,
                              void* d_out, int out_size, void* d_ws, size_t ws_size,
                              hipStream_t stream)
{
    const float* x     = (const float*)d_in[0];   // (B,S,D)
    const float* w_qkv = (const float*)d_in[1];   // (D,3D)
    const float* w_out = (const float*)d_in[2];   // (D,D)
    float* out = (float*)d_out;                   // (B,S,D) f32

    u16* xb    = (u16*)d_ws;                      // [4096][1024]
    u16* wqkvT = xb    + (size_t)4096 * 1024;     // [3072][1024]
    u16* woutT = wqkvT + (size_t)3072 * 1024;     // [1024][1024]
    u16* Qws   = woutT + (size_t)1024 * 1024;     // [32][2048][64]  (SC2-scaled)
    u16* Kws   = Qws   + (size_t)32 * 2048 * 64;
    u16* Vtws  = Kws   + (size_t)32 * 2048 * 64;  // [32][64][2048]
    u16* Ob    = Vtws  + (size_t)32 * 2048 * 64;  // [4096][1024] bf16
    u16* Opart = Ob    + (size_t)4096 * 1024;     // [1152][128][64] bf16 partials
    float* Oml = (float*)(Opart + (size_t)1152 * 128 * 64);  // [1152][128][2] f32

    prep<<<3072, 256, 0, stream>>>(x, xb, w_qkv, wqkvT, w_out, woutT);
    gemm_mfma<128><<<dim3(24, 32), 256, 0, stream>>>(xb, wqkvT, 0, Qws, Kws, Vtws, nullptr);
    attn_seg<<<1280, 256, 0, stream>>>(Qws, Kws, Vtws, Ob, Opart, Oml);
    attn_combine<<<dim3(12, 32), 256, 0, stream>>>(Opart, Oml, Ob);
    gemm_mfma<64><<<dim3(16, 32), 256, 0, stream>>>(Ob, woutT, 1, nullptr, nullptr, nullptr, out);
}